// Round 1
// baseline (837.689 us; speedup 1.0000x reference)
//
#include <hip/hip_runtime.h>
#include <hip/hip_bf16.h>

#define NNODE 50000
#define NEDGE 800000
#define NGRAPH 128
#define DIN 200
#define DH 128
#define OUTW (DIN + 4*DH)   // 712

typedef short bf16x8 __attribute__((ext_vector_type(8)));
typedef float f32x4  __attribute__((ext_vector_type(4)));

__device__ __forceinline__ short f2bf(float f) {
    union { float f; unsigned u; } x; x.f = f;
    unsigned u = x.u;
    u += 0x7fffu + ((u >> 16) & 1u);   // RNE
    return (short)(u >> 16);
}

// ---------------- utility ----------------
__global__ void zero_kernel(float* p, int n) {
    int i = blockIdx.x * 256 + threadIdx.x;
    if (i < n) p[i] = 0.f;
}

__global__ void gbounds_kernel(const int* __restrict__ gid, int* __restrict__ gs) {
    int g = threadIdx.x;
    if (g <= NGRAPH) {
        int lo = 0, hi = NNODE;
        while (lo < hi) { int m = (lo + hi) >> 1; if (gid[m] < g) lo = m + 1; else hi = m; }
        gs[g] = lo;
    }
}

// ---------------- CSR build ----------------
__global__ void count_kernel(const int* __restrict__ row, int* __restrict__ cnt) {
    int e = blockIdx.x * 256 + threadIdx.x;
    if (e < NEDGE) atomicAdd(&cnt[row[e]], 1);
}

__global__ void scan1_kernel(const int* __restrict__ cnt, int* __restrict__ off, int* __restrict__ bsum) {
    __shared__ int sd[256];
    int t = threadIdx.x, i = blockIdx.x * 256 + t;
    int v = (i < NNODE) ? cnt[i] : 0;
    sd[t] = v; __syncthreads();
    for (int s = 1; s < 256; s <<= 1) {
        int x = (t >= s) ? sd[t - s] : 0;
        __syncthreads(); sd[t] += x; __syncthreads();
    }
    if (i < NNODE) off[i] = sd[t] - v;     // exclusive within block
    if (t == 255) bsum[blockIdx.x] = sd[255];
}

__global__ void scan2_kernel(int* bsum, int nb) {
    __shared__ int sd[256];
    int t = threadIdx.x;
    int v = (t < nb) ? bsum[t] : 0;
    sd[t] = v; __syncthreads();
    for (int s = 1; s < 256; s <<= 1) {
        int x = (t >= s) ? sd[t - s] : 0;
        __syncthreads(); sd[t] += x; __syncthreads();
    }
    if (t < nb) bsum[t] = sd[t] - v;       // exclusive block offsets
}

__global__ void scan3_kernel(int* off, const int* __restrict__ bsum, int* cursor) {
    int t = threadIdx.x, i = blockIdx.x * 256 + t;
    if (i < NNODE) { off[i] += bsum[blockIdx.x]; cursor[i] = 0; }
    if (i == 0) off[NNODE] = NEDGE;
}

__global__ void fill_kernel(const int* __restrict__ row, const int* __restrict__ col,
                            const int* __restrict__ off, int* __restrict__ cursor,
                            int* __restrict__ ccol) {
    int e = blockIdx.x * 256 + threadIdx.x;
    if (e < NEDGE) {
        int r = row[e];
        int p = atomicAdd(&cursor[r], 1);
        ccol[off[r] + p] = col[e];
    }
}

// ---------------- GEMM: C[M][128] = act(A[M][KREAL]) @ W[KREAL][128], bf16 MFMA ----------------
template<int KSTEPS, int KREAL, bool FUSE>
__global__ __launch_bounds__(256) void gemm_kernel(
    const float* __restrict__ A, const float* __restrict__ W,
    const float* __restrict__ alpha, const float* __restrict__ beta,
    float* __restrict__ C, int M)
{
    constexpr int KP  = KSTEPS * 32;
    constexpr int LDK = KP + 8;                 // pad to dodge LDS bank conflicts
    __shared__ short lw[DH * LDK];              // W^T as bf16: [col][k]
    __shared__ float lal[DH], lbe[DH];
    int tid = threadIdx.x;
    if constexpr (FUSE) {
        if (tid < DH) { lal[tid] = alpha[tid]; lbe[tid] = beta[tid]; }
    }
    for (int idx = tid; idx < DH * KP; idx += 256) {
        int k = idx >> 7, c = idx & 127;
        float v = (k < KREAL) ? W[k * DH + c] : 0.f;
        lw[c * LDK + k] = f2bf(v);
    }
    __syncthreads();

    int wave = tid >> 6, lane = tid & 63;
    int r    = blockIdx.x * 64 + wave * 16 + (lane & 15);
    int ksub = (lane >> 4) * 8;
    bool rok = (r < M);
    const float* arow = A + (size_t)r * KREAL;

    f32x4 acc[8];
    #pragma unroll
    for (int n = 0; n < 8; ++n) acc[n] = (f32x4){0.f, 0.f, 0.f, 0.f};

    #pragma unroll
    for (int kk = 0; kk < KSTEPS; ++kk) {
        int k0 = kk * 32 + ksub;
        float va[8];
        if (rok && k0 < KREAL) {
            const float4* p = (const float4*)(arow + k0);
            float4 u0 = p[0], u1 = p[1];
            va[0]=u0.x; va[1]=u0.y; va[2]=u0.z; va[3]=u0.w;
            va[4]=u1.x; va[5]=u1.y; va[6]=u1.z; va[7]=u1.w;
        } else {
            #pragma unroll
            for (int e = 0; e < 8; ++e) va[e] = 0.f;
        }
        if constexpr (FUSE) {
            #pragma unroll
            for (int e = 0; e < 8; ++e) {
                int k = k0 + e;
                va[e] = fmaxf(lal[k] * va[e] + lbe[k], 0.f);
            }
        }
        bf16x8 a;
        #pragma unroll
        for (int e = 0; e < 8; ++e) a[e] = f2bf(va[e]);
        #pragma unroll
        for (int n = 0; n < 8; ++n) {
            bf16x8 b = *(const bf16x8*)&lw[(n * 16 + (lane & 15)) * LDK + kk * 32 + ksub];
            acc[n] = __builtin_amdgcn_mfma_f32_16x16x32_bf16(a, b, acc[n], 0, 0, 0);
        }
    }

    int rbase = blockIdx.x * 64 + wave * 16 + (lane >> 4) * 4;
    int cb = lane & 15;
    #pragma unroll
    for (int n = 0; n < 8; ++n) {
        #pragma unroll
        for (int j = 0; j < 4; ++j) {
            int rr = rbase + j;
            if (rr < M) C[(size_t)rr * DH + n * 16 + cb] = acc[n][j];
        }
    }
}

// ---------------- aggregation: z = Adj@y + (1+eps)*y ----------------
__global__ __launch_bounds__(64) void agg_kernel(
    const float* __restrict__ y, float* __restrict__ z,
    const int* __restrict__ off, const int* __restrict__ ccol,
    const float* __restrict__ epsv, int layer)
{
    int node = blockIdx.x, t = threadIdx.x;
    int k = off[node], k1 = off[node + 1];
    const float2* y2 = (const float2*)y;
    float ax = 0.f, ay = 0.f, bx = 0.f, by = 0.f;
    for (; k + 1 < k1; k += 2) {
        int c0 = ccol[k], c1 = ccol[k + 1];
        float2 v0 = y2[(size_t)c0 * 64 + t];
        float2 v1 = y2[(size_t)c1 * 64 + t];
        ax += v0.x; ay += v0.y; bx += v1.x; by += v1.y;
    }
    if (k < k1) { float2 v = y2[(size_t)ccol[k] * 64 + t]; ax += v.x; ay += v.y; }
    float e = 1.f + epsv[layer];
    float2 sv = y2[(size_t)node * 64 + t];
    float2 r; r.x = ax + bx + e * sv.x; r.y = ay + by + e * sv.y;
    ((float2*)z)[(size_t)node * 64 + t] = r;
}

// ---------------- BN stats (two-phase) ----------------
__global__ __launch_bounds__(256) void stats_kernel(const float* __restrict__ z,
                                                    float* __restrict__ ps, float* __restrict__ pq) {
    __shared__ float ls[256], lq[256];
    int b = blockIdx.x, t = threadIdx.x;
    int col = t & 127, h = t >> 7;
    int r0 = b * 196, r1 = min(r0 + 196, NNODE);
    float s = 0.f, q = 0.f;
    for (int r = r0 + h; r < r1; r += 2) {
        float v = z[(size_t)r * DH + col];
        s += v; q += v * v;
    }
    ls[t] = s; lq[t] = q; __syncthreads();
    if (t < 128) {
        ps[b * DH + t] = ls[t] + ls[t + 128];
        pq[b * DH + t] = lq[t] + lq[t + 128];
    }
}

__global__ __launch_bounds__(128) void colparams_kernel(
    const float* __restrict__ ps, const float* __restrict__ pq,
    const float* __restrict__ gamma, const float* __restrict__ bbeta,
    float* __restrict__ al, float* __restrict__ be)
{
    int c = threadIdx.x;
    float s = 0.f, q = 0.f;
    for (int i = 0; i < 256; ++i) { s += ps[i * DH + c]; q += pq[i * DH + c]; }
    float mean = s * (1.0f / NNODE);
    float var  = fmaxf(q * (1.0f / NNODE) - mean * mean, 0.f);
    float inv  = rsqrtf(var + 1e-5f);
    float a    = gamma[c] * inv;
    al[c] = a; be[c] = bbeta[c] - a * mean;
}

// ---------------- pooling ----------------
__global__ __launch_bounds__(256) void poolx_kernel(const float* __restrict__ x,
                                                    const int* __restrict__ gs, float* __restrict__ out) {
    int g = blockIdx.x >> 3, s = blockIdx.x & 7, c = threadIdx.x;
    if (c >= DIN) return;
    int lo = gs[g], hi = gs[g + 1], len = hi - lo;
    int r0 = lo + (len * s >> 3), r1 = lo + (len * (s + 1) >> 3);
    float acc = 0.f;
    for (int r = r0; r < r1; ++r) acc += x[(size_t)r * DIN + c];
    atomicAdd(&out[g * OUTW + c], acc);
}

__global__ __launch_bounds__(128) void pool_kernel(const float* __restrict__ rep,
                                                   const float* __restrict__ al, const float* __restrict__ be,
                                                   const int* __restrict__ gs, float* __restrict__ out, int ooff) {
    int g = blockIdx.x >> 3, s = blockIdx.x & 7, c = threadIdx.x;
    int lo = gs[g], hi = gs[g + 1], len = hi - lo;
    int r0 = lo + (len * s >> 3), r1 = lo + (len * (s + 1) >> 3);
    float a = al[c], b = be[c], acc = 0.f;
    for (int r = r0; r < r1; ++r) acc += fmaxf(a * rep[(size_t)r * DH + c] + b, 0.f);
    atomicAdd(&out[g * OUTW + ooff + c], acc);
}

// ---------------- launch ----------------
extern "C" void kernel_launch(void* const* d_in, const int* in_sizes, int n_in,
                              void* d_out, int out_size, void* d_ws, size_t ws_size,
                              hipStream_t stream)
{
    const float* x    = (const float*)d_in[0];
    const int*   erow = (const int*)d_in[1];
    const int*   ecol = (const int*)d_in[2];
    const int*   gid  = (const int*)d_in[3];
    const float* eps  = (const float*)d_in[4];
    const float* w1_0 = (const float*)d_in[5];
    const float* g1_0 = (const float*)d_in[7];
    const float* be10 = (const float*)d_in[8];
    const float* w2_0 = (const float*)d_in[9];
    const float* gbn0 = (const float*)d_in[11];
    const float* bbn0 = (const float*)d_in[12];
    const float* w1_r = (const float*)d_in[13];
    const float* g1_r = (const float*)d_in[15];
    const float* be1r = (const float*)d_in[16];
    const float* w2_r = (const float*)d_in[17];
    const float* gbnr = (const float*)d_in[19];
    const float* bbnr = (const float*)d_in[20];
    float* out = (float*)d_out;

    float* ws = (float*)d_ws;
    float* Y  = ws;
    float* Z  = Y  + (size_t)NNODE * DH;
    float* RA = Z  + (size_t)NNODE * DH;
    float* RB = RA + (size_t)NNODE * DH;
    float* ps = RB + (size_t)NNODE * DH;
    float* pq = ps + 256 * DH;
    float* a1 = pq + 256 * DH;
    float* b1 = a1 + DH;
    float* a2 = b1 + DH;
    float* b2 = a2 + DH;
    int* cnt    = (int*)(b2 + DH);
    int* off    = cnt + NNODE;
    int* cursor = off + NNODE + 8;
    int* ccol   = cursor + NNODE;
    int* bsum   = ccol + NEDGE;
    int* gs     = bsum + 256;

    // init + CSR build + graph bounds
    zero_kernel<<<(OUTW * NGRAPH + 255) / 256, 256, 0, stream>>>(out, OUTW * NGRAPH);
    zero_kernel<<<(NNODE + 255) / 256, 256, 0, stream>>>((float*)cnt, NNODE);
    gbounds_kernel<<<1, 256, 0, stream>>>(gid, gs);
    count_kernel<<<(NEDGE + 255) / 256, 256, 0, stream>>>(erow, cnt);
    scan1_kernel<<<196, 256, 0, stream>>>(cnt, off, bsum);
    scan2_kernel<<<1, 256, 0, stream>>>(bsum, 196);
    scan3_kernel<<<196, 256, 0, stream>>>(off, bsum, cursor);
    fill_kernel<<<(NEDGE + 255) / 256, 256, 0, stream>>>(erow, ecol, off, cursor, ccol);
    poolx_kernel<<<NGRAPH * 8, 256, 0, stream>>>(x, gs, out);

    const int GB = (NNODE + 63) / 64;  // 782
    for (int l = 0; l < 4; ++l) {
        const float* W1 = (l == 0) ? w1_0 : (w1_r + (size_t)(l - 1) * DH * DH);
        const float* W2 = (l == 0) ? w2_0 : (w2_r + (size_t)(l - 1) * DH * DH);
        const float* G1 = (l == 0) ? g1_0 : (g1_r + (l - 1) * DH);
        const float* B1 = (l == 0) ? be10 : (be1r + (l - 1) * DH);
        const float* G2 = (l == 0) ? gbn0 : (gbnr + (l - 1) * DH);
        const float* B2 = (l == 0) ? bbn0 : (bbnr + (l - 1) * DH);
        float* rep = (l & 1) ? RB : RA;

        if (l == 0)
            gemm_kernel<7, 200, false><<<GB, 256, 0, stream>>>(x, W1, nullptr, nullptr, Y, NNODE);
        else {
            const float* prev = ((l - 1) & 1) ? RB : RA;
            gemm_kernel<4, 128, true><<<GB, 256, 0, stream>>>(prev, W1, a2, b2, Y, NNODE);
        }
        agg_kernel<<<NNODE, 64, 0, stream>>>(Y, Z, off, ccol, eps, l);
        stats_kernel<<<256, 256, 0, stream>>>(Z, ps, pq);
        colparams_kernel<<<1, 128, 0, stream>>>(ps, pq, G1, B1, a1, b1);
        gemm_kernel<4, 128, true><<<GB, 256, 0, stream>>>(Z, W2, a1, b1, rep, NNODE);
        stats_kernel<<<256, 256, 0, stream>>>(rep, ps, pq);
        colparams_kernel<<<1, 128, 0, stream>>>(ps, pq, G2, B2, a2, b2);
        pool_kernel<<<NGRAPH * 8, 128, 0, stream>>>(rep, a2, b2, gs, out, DIN + l * DH);
    }
}

// Round 2
// 767.286 us; speedup vs baseline: 1.0918x; 1.0918x over previous
//
#include <hip/hip_runtime.h>
#include <hip/hip_bf16.h>

#define NNODE 50000
#define NEDGE 800000
#define NGRAPH 128
#define DIN 200
#define DH 128
#define OUTW (DIN + 4*DH)   // 712

typedef short bf16x8 __attribute__((ext_vector_type(8)));
typedef float f32x4  __attribute__((ext_vector_type(4)));

__device__ __forceinline__ short f2bf(float f) {
    union { float f; unsigned u; } x; x.f = f;
    unsigned u = x.u;
    u += 0x7fffu + ((u >> 16) & 1u);   // RNE
    return (short)(u >> 16);
}
__device__ __forceinline__ float bflo(unsigned v) {
    union { unsigned u; float f; } x; x.u = v << 16; return x.f;
}
__device__ __forceinline__ float bfhi(unsigned v) {
    union { unsigned u; float f; } x; x.u = v & 0xffff0000u; return x.f;
}
__device__ __forceinline__ unsigned pkbf(float lo, float hi) {
    __hip_bfloat162 p = __float22bfloat162_rn(float2{lo, hi});
    unsigned u; __builtin_memcpy(&u, &p, 4); return u;
}

// ---------------- utility ----------------
__global__ void zero_kernel(float* p, int n) {
    int i = blockIdx.x * 256 + threadIdx.x;
    if (i < n) p[i] = 0.f;
}

__global__ void gbounds_kernel(const int* __restrict__ gid, int* __restrict__ gs) {
    int g = threadIdx.x;
    if (g <= NGRAPH) {
        int lo = 0, hi = NNODE;
        while (lo < hi) { int m = (lo + hi) >> 1; if (gid[m] < g) lo = m + 1; else hi = m; }
        gs[g] = lo;
    }
}

// convert all 8 weight matrices to bf16 W^T [col][kpad] once per call
__global__ void wconv_kernel(const float* __restrict__ w1_0, const float* __restrict__ w2_0,
                             const float* __restrict__ w1_r, const float* __restrict__ w2_r,
                             short* __restrict__ Wt) {
    int m = blockIdx.y;
    int idx = blockIdx.x * 256 + threadIdx.x;
    int KP = (m == 0) ? 224 : 128;
    if (idx >= KP * DH) return;
    int k = idx >> 7, c = idx & 127;
    const float* src = (m == 0) ? w1_0 : (m == 1) ? w2_0
                     : ((m & 1) == 0 ? w1_r + (size_t)((m - 2) >> 1) * DH * DH
                                     : w2_r + (size_t)((m - 3) >> 1) * DH * DH);
    int KREAL = (m == 0) ? 200 : 128;
    float v = (k < KREAL) ? src[k * DH + c] : 0.f;
    short* dst = Wt + ((m == 0) ? 0 : 28672 + (m - 1) * 16384);
    dst[c * KP + k] = f2bf(v);
}

// ---------------- CSR build ----------------
__global__ void count_kernel(const int* __restrict__ row, int* __restrict__ cnt) {
    int e = blockIdx.x * 256 + threadIdx.x;
    if (e < NEDGE) atomicAdd(&cnt[row[e]], 1);
}

__global__ void scan1_kernel(const int* __restrict__ cnt, int* __restrict__ off, int* __restrict__ bsum) {
    __shared__ int sd[256];
    int t = threadIdx.x, i = blockIdx.x * 256 + t;
    int v = (i < NNODE) ? cnt[i] : 0;
    sd[t] = v; __syncthreads();
    for (int s = 1; s < 256; s <<= 1) {
        int x = (t >= s) ? sd[t - s] : 0;
        __syncthreads(); sd[t] += x; __syncthreads();
    }
    if (i < NNODE) off[i] = sd[t] - v;
    if (t == 255) bsum[blockIdx.x] = sd[255];
}

__global__ void scan2_kernel(int* bsum, int nb) {
    __shared__ int sd[256];
    int t = threadIdx.x;
    int v = (t < nb) ? bsum[t] : 0;
    sd[t] = v; __syncthreads();
    for (int s = 1; s < 256; s <<= 1) {
        int x = (t >= s) ? sd[t - s] : 0;
        __syncthreads(); sd[t] += x; __syncthreads();
    }
    if (t < nb) bsum[t] = sd[t] - v;
}

__global__ void scan3_kernel(int* off, const int* __restrict__ bsum, int* cursor) {
    int t = threadIdx.x, i = blockIdx.x * 256 + t;
    if (i < NNODE) { off[i] += bsum[blockIdx.x]; cursor[i] = 0; }
    if (i == 0) off[NNODE] = NEDGE;
}

__global__ void fill_kernel(const int* __restrict__ row, const int* __restrict__ col,
                            const int* __restrict__ off, int* __restrict__ cursor,
                            int* __restrict__ ccol) {
    int e = blockIdx.x * 256 + threadIdx.x;
    if (e < NEDGE) {
        int r = row[e];
        int p = atomicAdd(&cursor[r], 1);
        ccol[off[r] + p] = col[e];
    }
}

// ---------------- GEMM: C[M][128] = act(A[M][KREAL]) @ W, B frags direct from global bf16 W^T ----------------
template<int KSTEPS, int KREAL, bool FUSE, bool STATS, bool BF16OUT>
__global__ __launch_bounds__(256) void gemm_kernel(
    const float* __restrict__ A, const short* __restrict__ Wt,
    const float* __restrict__ alpha, const float* __restrict__ beta,
    void* __restrict__ Cv, int M, float* __restrict__ ps, float* __restrict__ pq)
{
    constexpr int KP = KSTEPS * 32;
    __shared__ float sS[DH], sQ[DH];
    int tid = threadIdx.x;
    if constexpr (STATS) {
        if (tid < DH) { sS[tid] = 0.f; sQ[tid] = 0.f; }
        __syncthreads();
    }
    int wave = tid >> 6, lane = tid & 63;
    int lr = lane & 15, lk = lane >> 4;
    int row  = blockIdx.x * 64 + wave * 16 + lr;
    int ksub = lk * 8;
    bool rok = row < M;
    const float* arow = A + (size_t)row * KREAL;

    f32x4 acc[8];
    #pragma unroll
    for (int n = 0; n < 8; ++n) acc[n] = (f32x4){0.f, 0.f, 0.f, 0.f};

    #pragma unroll
    for (int kk = 0; kk < KSTEPS; ++kk) {
        int k0 = kk * 32 + ksub;
        float va[8];
        if (rok && (k0 + 8 <= KREAL)) {
            const float4* p = (const float4*)(arow + k0);
            float4 u0 = p[0], u1 = p[1];
            va[0]=u0.x; va[1]=u0.y; va[2]=u0.z; va[3]=u0.w;
            va[4]=u1.x; va[5]=u1.y; va[6]=u1.z; va[7]=u1.w;
        } else {
            #pragma unroll
            for (int e = 0; e < 8; ++e) va[e] = 0.f;
        }
        if constexpr (FUSE) {
            const float4* ap = (const float4*)(alpha + k0);
            const float4* bp = (const float4*)(beta + k0);
            float4 A0 = ap[0], A1 = ap[1], B0 = bp[0], B1 = bp[1];
            va[0]=fmaxf(A0.x*va[0]+B0.x,0.f); va[1]=fmaxf(A0.y*va[1]+B0.y,0.f);
            va[2]=fmaxf(A0.z*va[2]+B0.z,0.f); va[3]=fmaxf(A0.w*va[3]+B0.w,0.f);
            va[4]=fmaxf(A1.x*va[4]+B1.x,0.f); va[5]=fmaxf(A1.y*va[5]+B1.y,0.f);
            va[6]=fmaxf(A1.z*va[6]+B1.z,0.f); va[7]=fmaxf(A1.w*va[7]+B1.w,0.f);
        }
        union { bf16x8 v; unsigned u[4]; } a;
        #pragma unroll
        for (int e2 = 0; e2 < 4; ++e2) a.u[e2] = pkbf(va[2*e2], va[2*e2+1]);
        #pragma unroll
        for (int n = 0; n < 8; ++n) {
            bf16x8 b = *(const bf16x8*)(Wt + (size_t)(n * 16 + lr) * KP + kk * 32 + ksub);
            acc[n] = __builtin_amdgcn_mfma_f32_16x16x32_bf16(a.v, b, acc[n], 0, 0, 0);
        }
    }

    int orow = blockIdx.x * 64 + wave * 16 + lk * 4;
    #pragma unroll
    for (int n = 0; n < 8; ++n) {
        #pragma unroll
        for (int j = 0; j < 4; ++j) {
            int rr = orow + j;
            if (rr < M) {
                if constexpr (BF16OUT)
                    ((short*)Cv)[(size_t)rr * DH + n * 16 + lr] = f2bf(acc[n][j]);
                else
                    ((float*)Cv)[(size_t)rr * DH + n * 16 + lr] = acc[n][j];
            }
        }
    }

    if constexpr (STATS) {
        #pragma unroll
        for (int n = 0; n < 8; ++n) {
            float s = 0.f, q = 0.f;
            #pragma unroll
            for (int j = 0; j < 4; ++j) {
                if (orow + j < M) { float v = acc[n][j]; s += v; q += v * v; }
            }
            atomicAdd(&sS[n * 16 + lr], s);
            atomicAdd(&sQ[n * 16 + lr], q);
        }
        __syncthreads();
        if (tid < DH) { atomicAdd(&ps[tid], sS[tid]); atomicAdd(&pq[tid], sQ[tid]); }
    }
}

// ---------------- aggregation: z = Adj@y + (1+eps)*y  (y is bf16) ----------------
__global__ __launch_bounds__(256) void agg_kernel(
    const short* __restrict__ yb, float* __restrict__ z,
    const int* __restrict__ off, const int* __restrict__ ccol,
    const float* __restrict__ epsv, int layer)
{
    int wave = threadIdx.x >> 6, t = threadIdx.x & 63;
    int node = blockIdx.x * 4 + wave;
    if (node >= NNODE) return;
    const unsigned* y2 = (const unsigned*)yb;
    int k = off[node], k1 = off[node + 1];
    float s0=0,s1=0,t0=0,t1=0,u0=0,u1=0,v0=0,v1=0;
    for (; k + 3 < k1; k += 4) {
        int c0 = ccol[k], c1 = ccol[k+1], c2 = ccol[k+2], c3 = ccol[k+3];
        unsigned a = y2[(size_t)c0 * 64 + t];
        unsigned b = y2[(size_t)c1 * 64 + t];
        unsigned c = y2[(size_t)c2 * 64 + t];
        unsigned d = y2[(size_t)c3 * 64 + t];
        s0 += bflo(a); s1 += bfhi(a); t0 += bflo(b); t1 += bfhi(b);
        u0 += bflo(c); u1 += bfhi(c); v0 += bflo(d); v1 += bfhi(d);
    }
    for (; k < k1; ++k) {
        unsigned a = y2[(size_t)ccol[k] * 64 + t];
        s0 += bflo(a); s1 += bfhi(a);
    }
    unsigned sv = y2[(size_t)node * 64 + t];
    float e = 1.f + epsv[layer];
    float2 r;
    r.x = (s0 + t0) + (u0 + v0) + e * bflo(sv);
    r.y = (s1 + t1) + (u1 + v1) + e * bfhi(sv);
    ((float2*)z)[(size_t)node * 64 + t] = r;
}

// ---------------- BN stats over Z (two-phase) ----------------
__global__ __launch_bounds__(256) void stats_kernel(const float* __restrict__ z,
                                                    float* __restrict__ ps, float* __restrict__ pq) {
    __shared__ float ls[256], lq[256];
    int b = blockIdx.x, t = threadIdx.x;
    int col = t & 127, h = t >> 7;
    int r0 = b * 196, r1 = min(r0 + 196, NNODE);
    float s = 0.f, q = 0.f;
    for (int r = r0 + h; r < r1; r += 2) {
        float v = z[(size_t)r * DH + col];
        s += v; q += v * v;
    }
    ls[t] = s; lq[t] = q; __syncthreads();
    if (t < 128) {
        ps[b * DH + t] = ls[t] + ls[t + 128];
        pq[b * DH + t] = lq[t] + lq[t + 128];
    }
}

__global__ __launch_bounds__(128) void colparams_kernel(
    const float* __restrict__ ps, const float* __restrict__ pq,
    const float* __restrict__ gamma, const float* __restrict__ bbeta,
    float* __restrict__ al, float* __restrict__ be)
{
    int c = threadIdx.x;
    float s = 0.f, q = 0.f;
    for (int i = 0; i < 256; ++i) { s += ps[i * DH + c]; q += pq[i * DH + c]; }
    float mean = s * (1.0f / NNODE);
    float var  = fmaxf(q * (1.0f / NNODE) - mean * mean, 0.f);
    float inv  = rsqrtf(var + 1e-5f);
    float a    = gamma[c] * inv;
    al[c] = a; be[c] = bbeta[c] - a * mean;
}

__global__ __launch_bounds__(128) void colparams_fused_kernel(
    float* __restrict__ ps, float* __restrict__ pq,
    const float* __restrict__ gamma, const float* __restrict__ bbeta,
    float* __restrict__ al, float* __restrict__ be)
{
    int c = threadIdx.x;
    float s = ps[c], q = pq[c];
    float mean = s * (1.0f / NNODE);
    float var  = fmaxf(q * (1.0f / NNODE) - mean * mean, 0.f);
    float inv  = rsqrtf(var + 1e-5f);
    float a    = gamma[c] * inv;
    al[c] = a; be[c] = bbeta[c] - a * mean;
    ps[c] = 0.f; pq[c] = 0.f;   // ready for next fused-stats GEMM
}

// ---------------- pooling ----------------
__global__ __launch_bounds__(256) void poolx_kernel(const float* __restrict__ x,
                                                    const int* __restrict__ gs, float* __restrict__ out) {
    int g = blockIdx.x >> 3, s = blockIdx.x & 7, c = threadIdx.x;
    if (c >= DIN) return;
    int lo = gs[g], hi = gs[g + 1], len = hi - lo;
    int r0 = lo + (len * s >> 3), r1 = lo + (len * (s + 1) >> 3);
    float acc = 0.f;
    for (int r = r0; r < r1; ++r) acc += x[(size_t)r * DIN + c];
    atomicAdd(&out[g * OUTW + c], acc);
}

__global__ __launch_bounds__(128) void pool_kernel(const float* __restrict__ rep,
                                                   const float* __restrict__ al, const float* __restrict__ be,
                                                   const int* __restrict__ gs, float* __restrict__ out, int ooff) {
    int g = blockIdx.x >> 3, s = blockIdx.x & 7, c = threadIdx.x;
    int lo = gs[g], hi = gs[g + 1], len = hi - lo;
    int r0 = lo + (len * s >> 3), r1 = lo + (len * (s + 1) >> 3);
    float a = al[c], b = be[c], acc = 0.f;
    for (int r = r0; r < r1; ++r) acc += fmaxf(a * rep[(size_t)r * DH + c] + b, 0.f);
    atomicAdd(&out[g * OUTW + ooff + c], acc);
}

// ---------------- launch ----------------
extern "C" void kernel_launch(void* const* d_in, const int* in_sizes, int n_in,
                              void* d_out, int out_size, void* d_ws, size_t ws_size,
                              hipStream_t stream)
{
    const float* x    = (const float*)d_in[0];
    const int*   erow = (const int*)d_in[1];
    const int*   ecol = (const int*)d_in[2];
    const int*   gid  = (const int*)d_in[3];
    const float* eps  = (const float*)d_in[4];
    const float* w1_0 = (const float*)d_in[5];
    const float* g1_0 = (const float*)d_in[7];
    const float* be10 = (const float*)d_in[8];
    const float* w2_0 = (const float*)d_in[9];
    const float* gbn0 = (const float*)d_in[11];
    const float* bbn0 = (const float*)d_in[12];
    const float* w1_r = (const float*)d_in[13];
    const float* g1_r = (const float*)d_in[15];
    const float* be1r = (const float*)d_in[16];
    const float* w2_r = (const float*)d_in[17];
    const float* gbnr = (const float*)d_in[19];
    const float* bbnr = (const float*)d_in[20];
    float* out = (float*)d_out;

    float* ws = (float*)d_ws;
    float* Z   = ws;
    float* RA  = Z   + (size_t)NNODE * DH;
    float* RB  = RA  + (size_t)NNODE * DH;
    float* ps  = RB  + (size_t)NNODE * DH;   // 256*DH Z-stats partials
    float* pq  = ps  + 256 * DH;
    float* psA = pq  + 256 * DH;             // DH fused rep stats
    float* pqA = psA + DH;
    float* a1  = pqA + DH;
    float* b1  = a1  + DH;
    float* a2  = b1  + DH;
    float* b2  = a2  + DH;
    short* Y   = (short*)(b2 + DH);          // NNODE*DH bf16
    short* Wt  = Y + (size_t)NNODE * DH;     // 28672 + 7*16384 = 143360 shorts
    int* cnt    = (int*)(Wt + 143360);
    int* off    = cnt + NNODE;
    int* cursor = off + NNODE + 8;
    int* ccol   = cursor + NNODE;
    int* bsum   = ccol + NEDGE;
    int* gs     = bsum + 256;

    zero_kernel<<<(OUTW * NGRAPH + 255) / 256, 256, 0, stream>>>(out, OUTW * NGRAPH);
    zero_kernel<<<(NNODE + 255) / 256, 256, 0, stream>>>((float*)cnt, NNODE);
    zero_kernel<<<1, 256, 0, stream>>>(psA, 2 * DH);
    gbounds_kernel<<<1, 256, 0, stream>>>(gid, gs);
    wconv_kernel<<<dim3(112, 8), 256, 0, stream>>>(w1_0, w2_0, w1_r, w2_r, Wt);
    count_kernel<<<(NEDGE + 255) / 256, 256, 0, stream>>>(erow, cnt);
    scan1_kernel<<<196, 256, 0, stream>>>(cnt, off, bsum);
    scan2_kernel<<<1, 256, 0, stream>>>(bsum, 196);
    scan3_kernel<<<196, 256, 0, stream>>>(off, bsum, cursor);
    fill_kernel<<<(NEDGE + 255) / 256, 256, 0, stream>>>(erow, ecol, off, cursor, ccol);
    poolx_kernel<<<NGRAPH * 8, 256, 0, stream>>>(x, gs, out);

    const int GB = (NNODE + 63) / 64;  // 782
    for (int l = 0; l < 4; ++l) {
        const short* Wt1 = (l == 0) ? Wt : Wt + 28672 + (size_t)(2 * l - 1) * 16384;
        const short* Wt2 = (l == 0) ? Wt + 28672 : Wt + 28672 + (size_t)(2 * l) * 16384;
        const float* G1 = (l == 0) ? g1_0 : (g1_r + (l - 1) * DH);
        const float* B1 = (l == 0) ? be10 : (be1r + (l - 1) * DH);
        const float* G2 = (l == 0) ? gbn0 : (gbnr + (l - 1) * DH);
        const float* B2 = (l == 0) ? bbn0 : (bbnr + (l - 1) * DH);
        float* rep = (l & 1) ? RB : RA;

        if (l == 0)
            gemm_kernel<7, 200, false, false, true><<<GB, 256, 0, stream>>>(
                x, Wt1, nullptr, nullptr, Y, NNODE, nullptr, nullptr);
        else {
            const float* prev = ((l - 1) & 1) ? RB : RA;
            gemm_kernel<4, 128, true, false, true><<<GB, 256, 0, stream>>>(
                prev, Wt1, a2, b2, Y, NNODE, nullptr, nullptr);
        }
        agg_kernel<<<(NNODE + 3) / 4, 256, 0, stream>>>(Y, Z, off, ccol, eps, l);
        stats_kernel<<<256, 256, 0, stream>>>(Z, ps, pq);
        colparams_kernel<<<1, 128, 0, stream>>>(ps, pq, G1, B1, a1, b1);
        gemm_kernel<4, 128, true, true, false><<<GB, 256, 0, stream>>>(
            Z, Wt2, a1, b1, rep, NNODE, psA, pqA);
        colparams_fused_kernel<<<1, 128, 0, stream>>>(psA, pqA, G2, B2, a2, b2);
        pool_kernel<<<NGRAPH * 8, 128, 0, stream>>>(rep, a2, b2, gs, out, DIN + l * DH);
    }
}